// Round 2
// 291.035 us; speedup vs baseline: 1.0025x; 1.0025x over previous
//
#include <hip/hip_runtime.h>
#include <stdint.h>

typedef __attribute__((ext_vector_type(8))) short short8;
typedef __attribute__((ext_vector_type(4))) float f32x4;

__device__ __forceinline__ unsigned short f32_to_bf16(float f) {
    unsigned int u = __float_as_uint(f);
    u += 0x7FFFu + ((u >> 16) & 1u);   // round-to-nearest-even
    return (unsigned short)(u >> 16);
}

__device__ __forceinline__ short8 load8_f32_as_bf16(const float* __restrict__ ap) {
    f32x4 f0 = *(const f32x4*)ap;
    f32x4 f1 = *(const f32x4*)(ap + 4);
    union { short8 s; unsigned short u[8]; } cv;
#pragma unroll
    for (int t = 0; t < 4; ++t) {
        cv.u[t]     = f32_to_bf16(f0[t]);
        cv.u[t + 4] = f32_to_bf16(f1[t]);
    }
    return cv.s;
}

// async global->LDS DMA, 16B/lane; LDS dest = wave-uniform base + lane*16 (m104/m108)
__device__ __forceinline__ void gld_lds16(const void* g, void* l) {
    __builtin_amdgcn_global_load_lds(
        (const __attribute__((address_space(1))) unsigned int*)(unsigned long long)(uintptr_t)g,
        (__attribute__((address_space(3))) unsigned int*)(unsigned int)(uintptr_t)l,
        16, 0, 0);
}

// cumulative count of 128-wide n-blocks for 64-row causal m-tiles 0..y-1
__device__ __forceinline__ int triC(int y) {
    int t = y >> 1;
    return y + t * (t - 1) + ((y & 1) ? t : 0);
}

// ---------------------------------------------------------------------------
// Old NT GEMM template (kept for the triangular attention launches: scores
// EPI=6 and PV EPI=4). Single-buffer 2-barrier per K-tile, MT x 128 tile,
// 4 waves. Swizzle chunk' = c ^ (row&7): SQ_LDS_BANK_CONFLICT == 0 (R4).
// ---------------------------------------------------------------------------
template<int AMODE, int EPI, int SWIZ, bool KLIMIT, int MT>
__global__ __launch_bounds__(256, 4)
void gemm128(const unsigned short* __restrict__ A, const unsigned short* __restrict__ A2,
             int lda, int lda2, int ksplit,
             const unsigned short* __restrict__ B, int ldb,
             void* __restrict__ C, int ldc, int K,
             long aStride, long bStride, long cStride,
             const float* __restrict__ bias, long biasStride, float scale,
             void* __restrict__ C2, int ldc2)
{
    int z = blockIdx.z;
    int mblk, nblk;
    if (SWIZ == 1) {
        int lin = blockIdx.y * gridDim.x + blockIdx.x;
        int mchunk = gridDim.y >> 3;
        int xcd = lin & 7, idx = lin >> 3;
        mblk = xcd * mchunk + idx % mchunk;   // m fast within XCD's chunk
        nblk = idx / mchunk;                  // n slow
    } else if (SWIZ == 4) {
        mblk = (z & 2) ? ((int)gridDim.y - 1 - (int)blockIdx.y) : blockIdx.y;
        nblk = blockIdx.x;
    } else if (SWIZ == 5) {
        int x = blockIdx.x;
        int a = (int)(2.f * sqrtf((float)x));
        if (a > 31) a = 31;
        while (a < 31 && triC(a + 1) <= x) ++a;
        while (a > 0 && triC(a) > x) --a;
        mblk = a;
        nblk = x - triC(a);
    } else if (SWIZ == 6) {
        int x = blockIdx.x, yy = blockIdx.y;
        if (z < 2) { mblk = x * 8 + (yy & 7); nblk = yy >> 3; }
        else       { nblk = x * 8 + (yy & 7); mblk = yy >> 3; }
    } else {
        mblk = blockIdx.y;
        nblk = blockIdx.x;
    }
    int m0 = mblk * MT;
    int n0 = nblk * 128;

    const unsigned short* Ab;
    const unsigned short* Bb;
    if (SWIZ == 6) {
        if (z < 2) { Ab = A; Bb = B + (size_t)z * bStride; }
        else       { Ab = B + (size_t)2 * bStride; Bb = A; }
    } else {
        Ab = A + (size_t)z * aStride;
        Bb = B + (size_t)z * bStride;
    }

    __shared__ __align__(16) short As[MT * 64];
    __shared__ __align__(16) short Bs[128 * 64];

    int tid  = threadIdx.x;
    int lane = tid & 63, wid = tid >> 6;
    constexpr int MI = MT / 32;              // a-frag / acc-row count per wave
    int wm = (wid & 1) * (MT / 2), wn = (wid >> 1) * 64;
    int fr = lane & 15, fq = lane >> 4;
    int sw0 = ((fq    ) ^ (fr & 7)) * 16;
    int sw1 = ((fq ^ 4) ^ (fr & 7)) * 16;

    int rS = tid >> 3;
    int cS = ((tid & 7) ^ (rS & 7)) * 8;   // element offset in k
    char* AsB = (char*)As; char* BsB = (char*)Bs;

    int kend = KLIMIT ? min(K, m0 + MT) : K;

    f32x4 acc[MI][4];
#pragma unroll
    for (int i = 0; i < MI; ++i)
#pragma unroll
    for (int j = 0; j < 4; ++j) acc[i][j] = f32x4{0.f, 0.f, 0.f, 0.f};

    for (int k0 = 0; k0 < kend; k0 += 64) {
        const unsigned short* Asrc = Ab;
        int koff = k0, ldax = lda;
        if (AMODE == 2 && k0 >= ksplit) { Asrc = A2; koff = k0 - ksplit; ldax = lda2; }
        const unsigned short* pa = Asrc + (size_t)(m0 + rS) * ldax + koff + cS;
        const unsigned short* pb = Bb   + (size_t)(n0 + rS) * ldb  + k0   + cS;
#pragma unroll
        for (int t = 0; t < MT / 32; ++t)
            gld_lds16(pa + (size_t)(32 * t) * ldax, AsB + t * 4096 + tid * 16);
#pragma unroll
        for (int t = 0; t < 4; ++t)
            gld_lds16(pb + (size_t)(32 * t) * ldb,  BsB + t * 4096 + tid * 16);
        __syncthreads();

#pragma unroll
        for (int kh = 0; kh < 2; ++kh) {
            int sw = kh ? sw1 : sw0;
            short8 a[MI], b[4];
#pragma unroll
            for (int i = 0; i < MI; ++i)
                a[i] = *(const short8*)(AsB + (wm + i * 16 + fr) * 128 + sw);
#pragma unroll
            for (int j = 0; j < 4; ++j)
                b[j] = *(const short8*)(BsB + (wn + j * 16 + fr) * 128 + sw);
#pragma unroll
            for (int i = 0; i < MI; ++i)
#pragma unroll
            for (int j = 0; j < 4; ++j)
                acc[i][j] = __builtin_amdgcn_mfma_f32_16x16x32_bf16(a[i], b[j], acc[i][j], 0, 0, 0);
        }
        __syncthreads();
    }

    // epilogue: C/D layout col = lane&15, row = (lane>>4)*4 + reg [m89/m91]
    if (EPI == 0) {
        unsigned short* Cz; int ldcz;
        if (SWIZ == 6 && z >= 2) { Cz = (unsigned short*)C2; ldcz = ldc2; }
        else { Cz = (unsigned short*)C + (size_t)z * cStride; ldcz = ldc; }
#pragma unroll
        for (int i = 0; i < MI; ++i)
#pragma unroll
        for (int j = 0; j < 4; ++j)
#pragma unroll
        for (int r = 0; r < 4; ++r) {
            int row = m0 + wm + i * 16 + fq * 4 + r;
            int col = n0 + wn + j * 16 + fr;
            Cz[(size_t)row * ldcz + col] = f32_to_bf16(acc[i][j][r]);
        }
    } else if (EPI == 6) {
        unsigned short* Cz = (unsigned short*)C + (size_t)z * cStride;
        float* rs = const_cast<float*>(bias) + z * biasStride;
#pragma unroll
        for (int i = 0; i < MI; ++i)
#pragma unroll
        for (int r = 0; r < 4; ++r) {
            int row = m0 + wm + i * 16 + fq * 4 + r;
            float s = 0.f;
#pragma unroll
            for (int j = 0; j < 4; ++j) {
                int col = n0 + wn + j * 16 + fr;
                float e = (col <= row) ? __expf(acc[i][j][r] * scale - 16.f) : 0.f;
                s += e;
                Cz[(size_t)row * ldc + col] = f32_to_bf16(e);
            }
            s += __shfl_xor(s, 1);
            s += __shfl_xor(s, 2);
            s += __shfl_xor(s, 4);
            s += __shfl_xor(s, 8);      // reduced over the 16 fr-lanes
            if (fr == 0) atomicAdd(&rs[row], s);
        }
    } else if (EPI == 4) {
        unsigned short* Cz = (unsigned short*)C + (size_t)z * cStride;
#pragma unroll
        for (int i = 0; i < MI; ++i)
#pragma unroll
        for (int r = 0; r < 4; ++r) {
            int row = m0 + wm + i * 16 + fq * 4 + r;
            float inv = 1.f / bias[z * biasStride + row];
#pragma unroll
            for (int j = 0; j < 4; ++j) {
                int col = n0 + wn + j * 16 + fr;
                Cz[(size_t)row * ldc + col] = f32_to_bf16(acc[i][j][r] * inv);
            }
        }
    } else {
#pragma unroll
        for (int i = 0; i < MI; ++i)
#pragma unroll
        for (int j = 0; j < 4; ++j)
#pragma unroll
        for (int r = 0; r < 4; ++r) {
            int row = m0 + wm + i * 16 + fq * 4 + r;
            int col = n0 + wn + j * 16 + fr;
            float v = acc[i][j][r];
            if (EPI == 2) {
                v += bias[col];
                v = v > 0.f ? v : 0.f;
                ((unsigned short*)C + (size_t)z * cStride)[(size_t)row * ldc + col] = f32_to_bf16(v);
            } else {   // 3
                ((float*)C + (size_t)z * cStride)[(size_t)row * ldc + col] = v + bias[col];
            }
        }
    }
}

// ---------------------------------------------------------------------------
// Deep-pipelined NT GEMM (T3+T4+T5), C[M,N] = A[M,K]*B[N,K]^T.
// BM=256 x BN=128, BK=64, 512 threads = 8 waves (4M x 2N, 64x64/wave, acc
// 4x4). 3-slot LDS ring (144 KB, 1 block/CU): stage tile t+2 while computing
// tile t; gate each tile with counted s_waitcnt vmcnt(6) (6 gld_lds per
// thread per tile, 12 in flight steady-state, wait == "tile t+1 landed") +
// raw s_barrier. NEVER vmcnt(0) in the main loop (the m97 ~900 TF ceiling
// IS the vmcnt(0) drain inside __syncthreads). asm "memory" clobbers pin
// IR-level motion; sched_barrier(0) after each s_barrier pins MIR-level
// scheduling (rule #18 class). Requires NT >= 2 (all call sites: NT>=16).
// Ring safety: slot written for tile t+2 was last read in iteration t-1,
// whose reads completed before the barrier that preceded this STAGE.
// SWIZ: 1 = XCD m-chunk (grid x*y blocks, gridDim.y % 8 == 0)
//       6 = fused qkv: z<2 q,k (m-chunk/XCD); z==2 vT swapped operands
//           (n-chunk/XCD), C2/ldc2 output. grid dim3(4,64,3).
// EPI: 0 bf16 | 2 relu(+bias[col]) bf16 | 3 +bias[col] fp32
// AMODE 2: A switches to A2 at k>=ksplit (MLP1 concat trick).
// ---------------------------------------------------------------------------
template<int AMODE, int EPI, int SWIZ>
__global__ __launch_bounds__(512, 2)
void gemm8p(const unsigned short* __restrict__ A, const unsigned short* __restrict__ A2,
            int lda, int lda2, int ksplit,
            const unsigned short* __restrict__ B, int ldb,
            void* __restrict__ C, int ldc, int K,
            long bStride, long cStride,
            const float* __restrict__ bias,
            void* __restrict__ C2, int ldc2)
{
    constexpr int BM = 256, BN = 128;
    int z = blockIdx.z;
    int lin = blockIdx.y * gridDim.x + blockIdx.x;
    int xcd = lin & 7, idx = lin >> 3;
    int mblk, nblk;
    if (SWIZ == 6) {
        // 256 blocks/z. z<2: 32m x 8n (4 m-tiles/XCD); z==2: 4m x 64n (8 n/XCD)
        if (z < 2) { mblk = xcd * 4 + (idx & 3); nblk = idx >> 2; }
        else       { nblk = xcd * 8 + (idx & 7); mblk = idx >> 3; }
    } else {
        int mch = (int)gridDim.y >> 3;       // NB_M per XCD
        mblk = xcd * mch + idx % mch;
        nblk = idx / mch;
    }
    int m0 = mblk * BM, n0 = nblk * BN;

    const unsigned short *Ab, *Bb;
    if (SWIZ == 6) {
        if (z < 2) { Ab = A; Bb = B + (size_t)z * bStride; }
        else       { Ab = B + (size_t)2 * bStride; Bb = A; }
    } else { Ab = A; Bb = B; }

    constexpr int ATILE = BM * 64;           // shorts (32 KB)
    constexpr int BTILE = BN * 64;           // shorts (16 KB)
    constexpr int TILE  = ATILE + BTILE;     // 48 KB per ring slot
    __shared__ __align__(16) short lds[3 * TILE];   // 144 KB of 160 KB

    int tid  = threadIdx.x;
    int lane = tid & 63, wid = tid >> 6;
    int wm = (wid & 3) * 64, wn = (wid >> 2) * 64;
    int fr = lane & 15, fq = lane >> 4;
    // fragment-read byte offsets: global chunk g = kh*4+fq at slot g^(row&7)
    int sw0 = ((fq    ) ^ (fr & 7)) * 16;
    int sw1 = ((fq ^ 4) ^ (fr & 7)) * 16;

    // staging: thread covers rows rS + 64u, pre-swizzled source chunk so the
    // linear LDS dest (base + tid*16) realizes slot = chunk ^ (row&7)
    int rS = tid >> 3;                       // 0..63
    int cS = ((tid & 7) ^ (rS & 7)) * 8;

    int NT = K >> 6;                         // all K % 64 == 0 here, NT >= 16

    f32x4 acc[4][4];
#pragma unroll
    for (int i = 0; i < 4; ++i)
#pragma unroll
    for (int j = 0; j < 4; ++j) acc[i][j] = f32x4{0.f, 0.f, 0.f, 0.f};

    auto STAGE = [&](int t, int slot) {      // 6 gld_lds per thread
        int k0 = t << 6;
        char* dst = (char*)(lds + slot * TILE);
        const unsigned short* Asrc = Ab; int koff = k0, ldax = lda;
        if (AMODE == 2 && k0 >= ksplit) { Asrc = A2; koff = k0 - ksplit; ldax = lda2; }
        const unsigned short* pa = Asrc + (size_t)(m0 + rS) * ldax + koff + cS;
        const unsigned short* pb = Bb   + (size_t)(n0 + rS) * ldb  + k0   + cS;
#pragma unroll
        for (int u = 0; u < 4; ++u)
            gld_lds16(pa + (size_t)(64 * u) * ldax, dst + u * 8192 + tid * 16);
#pragma unroll
        for (int u = 0; u < 2; ++u)
            gld_lds16(pb + (size_t)(64 * u) * ldb, dst + 32768 + u * 8192 + tid * 16);
    };

    // prologue: 2 tiles in flight, wait only for tile 0 (oldest 6 of 12)
    STAGE(0, 0);
    STAGE(1, 1);
    asm volatile("s_waitcnt vmcnt(6)" ::: "memory");
    __builtin_amdgcn_s_barrier();
    __builtin_amdgcn_sched_barrier(0);
    asm volatile("" ::: "memory");

    int sc = 0, ss = 2;                      // compute slot, stage slot
    for (int t = 0; t < NT; ++t) {
        if (t + 2 < NT) STAGE(t + 2, ss);    // slot being staged == slot read at t-1
        const char* AsB = (const char*)(lds + sc * TILE);
        const char* BsB = AsB + 32768;
#pragma unroll
        for (int kh = 0; kh < 2; ++kh) {
            int sw = kh ? sw1 : sw0;
            short8 a[4], b[4];
#pragma unroll
            for (int i = 0; i < 4; ++i)
                a[i] = *(const short8*)(AsB + (wm + i * 16 + fr) * 128 + sw);
#pragma unroll
            for (int j = 0; j < 4; ++j)
                b[j] = *(const short8*)(BsB + (wn + j * 16 + fr) * 128 + sw);
            __builtin_amdgcn_s_setprio(1);
#pragma unroll
            for (int i = 0; i < 4; ++i)
#pragma unroll
            for (int j = 0; j < 4; ++j)
                acc[i][j] = __builtin_amdgcn_mfma_f32_16x16x32_bf16(a[i], b[j], acc[i][j], 0, 0, 0);
            __builtin_amdgcn_s_setprio(0);
        }
        if (t + 1 < NT) {
            if (t + 2 < NT) { asm volatile("s_waitcnt vmcnt(6)" ::: "memory"); }
            else            { asm volatile("s_waitcnt vmcnt(0)" ::: "memory"); }
            __builtin_amdgcn_s_barrier();
            __builtin_amdgcn_sched_barrier(0);
            asm volatile("" ::: "memory");
        }
        sc = sc == 2 ? 0 : sc + 1;
        ss = ss == 2 ? 0 : ss + 1;
    }

    // epilogue: C/D layout col = lane&15, row = (lane>>4)*4 + reg [m89/m91]
    if (EPI == 0) {
        unsigned short* Cz; int ldcz;
        if (SWIZ == 6 && z >= 2) { Cz = (unsigned short*)C2; ldcz = ldc2; }
        else { Cz = (unsigned short*)C + (size_t)z * cStride; ldcz = ldc; }
#pragma unroll
        for (int i = 0; i < 4; ++i)
#pragma unroll
        for (int j = 0; j < 4; ++j)
#pragma unroll
        for (int r = 0; r < 4; ++r) {
            int row = m0 + wm + i * 16 + fq * 4 + r;
            int col = n0 + wn + j * 16 + fr;
            Cz[(size_t)row * ldcz + col] = f32_to_bf16(acc[i][j][r]);
        }
    } else if (EPI == 2) {
        unsigned short* Cz = (unsigned short*)C;
#pragma unroll
        for (int i = 0; i < 4; ++i)
#pragma unroll
        for (int j = 0; j < 4; ++j)
#pragma unroll
        for (int r = 0; r < 4; ++r) {
            int row = m0 + wm + i * 16 + fq * 4 + r;
            int col = n0 + wn + j * 16 + fr;
            float v = acc[i][j][r] + bias[col];
            v = v > 0.f ? v : 0.f;
            Cz[(size_t)row * ldc + col] = f32_to_bf16(v);
        }
    } else {   // EPI == 3: fp32 + bias
        float* Cz = (float*)C;
#pragma unroll
        for (int i = 0; i < 4; ++i)
#pragma unroll
        for (int j = 0; j < 4; ++j)
#pragma unroll
        for (int r = 0; r < 4; ++r) {
            int row = m0 + wm + i * 16 + fq * 4 + r;
            int col = n0 + wn + j * 16 + fr;
            Cz[(size_t)row * ldc + col] = acc[i][j][r] + bias[col];
        }
    }
}

// ---------------------------------------------------------------------------
// one prep launch: xb = bf16(x); WT = [Wq;Wk;Wv]^T; W1T; W2T; rsum = 0.
// ---------------------------------------------------------------------------
__device__ __forceinline__ void transpose_tile32(const float* __restrict__ in,
                                                 unsigned short* __restrict__ out,
                                                 int rows, int cols, int bx, int by, int tid)
{
    __shared__ float t[32][33];
    int tx = tid & 31, ty = tid >> 5;   // 32 x 8
    int r0 = by * 32, c0 = bx * 32;
#pragma unroll
    for (int i = 0; i < 4; ++i)
        t[ty + i * 8][tx] = in[(size_t)(r0 + ty + i * 8) * cols + c0 + tx];
    __syncthreads();
#pragma unroll
    for (int i = 0; i < 4; ++i)
        out[(size_t)(c0 + ty + i * 8) * rows + r0 + tx] = f32_to_bf16(t[tx][ty + i * 8]);
}

__global__ __launch_bounds__(256)
void prep_kernel(const float* __restrict__ x,
                 const float* __restrict__ Wq, const float* __restrict__ Wk,
                 const float* __restrict__ Wv, const float* __restrict__ W1,
                 const float* __restrict__ W2,
                 unsigned short* __restrict__ xb, unsigned short* __restrict__ WT,
                 unsigned short* __restrict__ W1T, unsigned short* __restrict__ W2T,
                 float* __restrict__ rsum)
{
    int idx = blockIdx.x;
    int tid = threadIdx.x;
    if (idx < 4096) {
        size_t i = ((size_t)idx * 256 + tid) * 8;
        *(short8*)(xb + i) = load8_f32_as_bf16(x + i);
    } else if (idx < 7168) {
        int t = idx - 4096;
        int w = t >> 10; t &= 1023;
        const float* in = w == 0 ? Wq : (w == 1 ? Wk : Wv);
        transpose_tile32(in, WT + (size_t)w * 1024 * 1024, 1024, 1024,
                         t & 31, t >> 5, tid);
    } else if (idx < 9216) {
        int t = idx - 7168;
        transpose_tile32(W1, W1T, 2048, 1024, t & 31, t >> 5, tid);
    } else if (idx < 10240) {
        int t = idx - 9216;
        transpose_tile32(W2, W2T, 1024, 1024, t & 31, t >> 5, tid);
    } else {
        int t = idx - 10240;
        f32x4 zero = {0.f, 0.f, 0.f, 0.f};
        float* p = rsum + ((size_t)t * 256 + tid) * 8;
        *(f32x4*)p = zero;
        *(f32x4*)(p + 4) = zero;
    }
}

// ---------------------------------------------------------------------------
extern "C" void kernel_launch(void* const* d_in, const int* in_sizes, int n_in,
                              void* d_out, int out_size, void* d_ws, size_t ws_size,
                              hipStream_t stream)
{
    const float* x  = (const float*)d_in[0];   // [8192,1024]
    const float* Wq = (const float*)d_in[1];
    const float* Wk = (const float*)d_in[2];
    const float* Wv = (const float*)d_in[3];
    const float* W1 = (const float*)d_in[4];   // [2048,1024]
    const float* b1 = (const float*)d_in[5];
    const float* W2 = (const float*)d_in[6];   // [1024,1024]
    const float* b2 = (const float*)d_in[7];
    float* out = (float*)d_out;                // [8192,1024] fp32

    size_t off = 0;
    auto alloc = [&](size_t bytes) {
        char* r = (char*)d_ws + off;
        off += (bytes + 255) & ~(size_t)255;
        return r;
    };
    const size_t TOK = (size_t)8192 * 1024;    // tokens x dim
    unsigned short* WT   = (unsigned short*)alloc((size_t)3072 * 1024 * 2);
    unsigned short* W1T  = (unsigned short*)alloc((size_t)1024 * 2048 * 2);
    unsigned short* W2T  = (unsigned short*)alloc((size_t)1024 * 1024 * 2);
    unsigned short* xb   = (unsigned short*)alloc(TOK * 2);
    unsigned short* vT   = (unsigned short*)alloc((size_t)1024 * 8192 * 2); // [d][b*2048+s]
    unsigned short* attn = (unsigned short*)alloc(TOK * 2);
    float*          rsum = (float*)         alloc((size_t)4 * 2048 * 4);
    unsigned short* q    = (unsigned short*)alloc(TOK * 2);
    unsigned short* k    = (unsigned short*)alloc(TOK * 2);
    unsigned short* S    = (unsigned short*)alloc((size_t)4 * 2048 * 2048 * 2);
    unsigned short* h1   = S;                  // S dead after PV; MLP1 out aliases it
    // peak ws use: ~131 MB

    // prep: xb, WT, W1T, W2T, rsum=0 in one launch
    prep_kernel<<<10244, 256, 0, stream>>>(x, Wq, Wk, Wv, W1, W2, xb, WT, W1T, W2T, rsum);

    // fused q,k,vT on the deep-pipelined template: 768 blocks = 3 exact
    // rounds of 256 CUs (z<2: q,k = xb @ Wqk^T; z==2: vT = WvT @ xb^T)
    gemm8p<0, 0, 6><<<dim3(4, 64, 3), 512, 0, stream>>>(
        xb, nullptr, 1024, 0, 0, WT, 1024, q, 1024, 1024,
        (long)1024 * 1024, (long)TOK, nullptr, vT, 8192);

    // scores+softmax fused on 64-row m-tiles: P = exp(q@k^T/32 - 16) (causal),
    // rowsums -> rsum. Triangular grid: 272 blocks/z = 1088 total (4.25/CU).
    gemm128<0, 6, 5, false, 64><<<dim3(272, 1, 4), 256, 0, stream>>>(
        q, nullptr, 1024, 0, 0, k, 1024, S, 2048, 1024,
        (long)2048 * 1024, (long)2048 * 1024, (long)2048 * 2048, rsum, 2048, 0.03125f,
        nullptr, 0);
    // attn = (P @ v) / rsum[row]  (64-row tiles, kend = m0+64; z-complement:
    // each CU's 4 resident blocks sum to constant 66 iters)
    gemm128<0, 4, 4, true, 64><<<dim3(8, 32, 4), 256, 0, stream>>>(
        S, nullptr, 2048, 0, 0, vT, 8192, attn, 1024, 2048,
        (long)2048 * 2048, (long)2048, (long)2048 * 1024, rsum, 2048, 0.f, nullptr, 0);

    // MLP1: h1 = relu([attn | x] @ W1 + b1), split-A concat trick,
    // 256 blocks = exactly 1/CU on the 256x128 pipeline
    gemm8p<2, 2, 1><<<dim3(8, 32, 1), 512, 0, stream>>>(
        attn, xb, 1024, 1024, 1024, W1T, 2048, h1, 1024, 2048,
        0, 0, b1, nullptr, 0);
    // MLP2: out = h1 @ W2 + b2 (fp32 to d_out), 256 blocks
    gemm8p<0, 3, 1><<<dim3(8, 32, 1), 512, 0, stream>>>(
        h1, nullptr, 1024, 0, 0, W2T, 1024, out, 1024, 1024,
        0, 0, b2, nullptr, 0);
}